// Round 3
// baseline (108.181 us; speedup 1.0000x reference)
//
#include <hip/hip_runtime.h>
#include <math.h>

#define NROWS 16384
#define KB 1024   // time buckets; floor(t*KB) is monotone in t, so
                  // bucket(b_j) > bucket(b_i)  =>  t_j > t_i exactly.

__device__ __forceinline__ float wave_reduce_sum(float v) {
    #pragma unroll
    for (int m = 32; m >= 1; m >>= 1) v += __shfl_xor(v, m, 64);
    return v;
}

__device__ __forceinline__ int bucket_of(float t) {
    int b = (int)(t * (float)KB);          // t in [0,1)
    return min(max(b, 0), KB - 1);
}

// ws layout (floats):
//   0       logits[N]
//   N       e_arr[N]
//   2N      b_arr[N]      (int)
//   3N      sorted_te[N]  (float2 -> 2N floats)
//   5N      offsets[KB+1] (int)
//   5N+KB+1 cursor[KB]    (int)
//   ...     S[KB] (float), acc[2] (float), done (int)

// Node 1: wave-per-row logits + exp + bucket id; block 0 zeroes acc/done.
__global__ __launch_bounds__(256) void k_logits(
    const float* __restrict__ feats, const float* __restrict__ proto,
    const float* __restrict__ times,
    float* __restrict__ logits, float* __restrict__ e_arr,
    int* __restrict__ b_arr, float* __restrict__ acc, int* __restrict__ done)
{
    if (blockIdx.x == 0) {
        if (threadIdx.x < 2) acc[threadIdx.x] = 0.0f;
        if (threadIdx.x == 2) *done = 0;
    }
    int wave = threadIdx.x >> 6, lane = threadIdx.x & 63;
    int row = blockIdx.x * 4 + wave;
    float2 f = ((const float2*)feats)[row * 64 + lane];
    float2 p = ((const float2*)proto)[lane];
    float d  = f.x * p.x + f.y * p.y;
    float n2 = f.x * f.x + f.y * f.y;
    float p2 = p.x * p.x + p.y * p.y;
    d  = wave_reduce_sum(d);
    n2 = wave_reduce_sum(n2);
    p2 = wave_reduce_sum(p2);
    if (lane == 0) {
        float invpn = 1.0f / fmaxf(sqrtf(p2), 1e-12f);
        float invfn = 1.0f / fmaxf(sqrtf(n2), 1e-12f);
        float logit = (d * invpn * invfn) / 0.07f;
        logits[row] = logit;
        e_arr[row]  = expf(logit);
        b_arr[row]  = bucket_of(times[row]);
    }
}

// Node 2: single block: histogram + per-bucket e-sums (LDS atomics), then
// inclusive scan -> exclusive offsets/cursor and strict-suffix sums S[b].
__global__ __launch_bounds__(1024) void k_scan(
    const int* __restrict__ b_arr, const float* __restrict__ e_arr,
    int* __restrict__ offsets, int* __restrict__ cursor, float* __restrict__ S)
{
    __shared__ int   hist[KB];
    __shared__ float es[KB];
    __shared__ int   wbh[16];
    __shared__ float wbe[16];
    __shared__ float tot_sh;
    int t = threadIdx.x;
    hist[t] = 0; es[t] = 0.0f;
    __syncthreads();
    #pragma unroll
    for (int k = 0; k < NROWS / 1024; ++k) {
        int r = t + k * 1024;
        int b = b_arr[r];
        atomicAdd(&hist[b], 1);
        atomicAdd(&es[b], e_arr[r]);
    }
    __syncthreads();
    int   h = hist[t];
    float e = es[t];
    int   hi = h;
    float ei = e;
    int lane = t & 63, wid = t >> 6;
    #pragma unroll
    for (int d = 1; d < 64; d <<= 1) {
        int   hu = __shfl_up(hi, d, 64);
        float eu = __shfl_up(ei, d, 64);
        if (lane >= d) { hi += hu; ei += eu; }
    }
    if (lane == 63) { wbh[wid] = hi; wbe[wid] = ei; }
    __syncthreads();
    if (t == 0) {
        int hb = 0; float eb = 0.0f;
        #pragma unroll
        for (int k = 0; k < 16; ++k) {
            int hn = wbh[k]; float en = wbe[k];
            wbh[k] = hb; wbe[k] = eb;
            hb += hn; eb += en;
        }
        tot_sh = eb;
    }
    __syncthreads();
    hi += wbh[wid];            // inclusive prefix over all KB buckets
    ei += wbe[wid];
    offsets[t] = hi - h;       // exclusive
    cursor[t]  = hi - h;
    S[t] = tot_sh - ei;        // sum over buckets strictly greater than t
    if (t == KB - 1) offsets[KB] = hi;  // == NROWS
}

// Node 3: scatter rows into bucket-sorted CSR as (t, e) float2 pairs.
__global__ __launch_bounds__(256) void k_scatter(
    const float* __restrict__ times, const float* __restrict__ e_arr,
    const int* __restrict__ b_arr, int* __restrict__ cursor,
    float2* __restrict__ ste)
{
    int r = blockIdx.x * 256 + threadIdx.x;
    int b = b_arr[r];
    int pos = atomicAdd(&cursor[b], 1);
    ste[pos] = make_float2(times[r], e_arr[r]);
}

// Node 4: denom (suffix + own-bucket exact compare) + loss reduce + final.
__global__ __launch_bounds__(256) void k_denom_loss(
    const float* __restrict__ times, const int* __restrict__ events,
    const float* __restrict__ w, const float* __restrict__ logits,
    const int* __restrict__ b_arr, const int* __restrict__ offsets,
    const float* __restrict__ S, const float2* __restrict__ ste,
    float* __restrict__ acc, int* __restrict__ done, float* __restrict__ out)
{
    int i = blockIdx.x * 256 + threadIdx.x;
    float ti = times[i];
    int b = b_arr[i];
    float denom = S[b];
    int p1 = offsets[b + 1];
    for (int p = offsets[b]; p < p1; ++p) {
        float2 v = ste[p];
        denom += (v.x >= ti) ? v.y : 0.0f;
    }
    float ev = (float)events[i];
    float wv = ev * w[i];
    float loss = -(logits[i] - logf(denom + 1e-8f)) * wv;
    loss = wave_reduce_sum(loss);
    wv   = wave_reduce_sum(wv);
    __shared__ float s1[4], s2[4];
    int wave = threadIdx.x >> 6, lane = threadIdx.x & 63;
    if (lane == 0) { s1[wave] = loss; s2[wave] = wv; }
    __syncthreads();
    if (threadIdx.x == 0) {
        atomicAdd(&acc[0], s1[0] + s1[1] + s1[2] + s1[3]);
        atomicAdd(&acc[1], s2[0] + s2[1] + s2[2] + s2[3]);
        __threadfence();
        int ticket = atomicAdd(done, 1);
        if (ticket == (int)gridDim.x - 1) {
            __threadfence();
            float L = atomicAdd(&acc[0], 0.0f);   // coherent device-scope read
            float W = atomicAdd(&acc[1], 0.0f);
            out[0] = L / (W + 1e-8f);
        }
    }
}

extern "C" void kernel_launch(void* const* d_in, const int* in_sizes, int n_in,
                              void* d_out, int out_size, void* d_ws, size_t ws_size,
                              hipStream_t stream) {
    const float* feats  = (const float*)d_in[0];
    const float* times  = (const float*)d_in[1];
    const int*   events = (const int*)d_in[2];
    const float* w      = (const float*)d_in[3];
    const float* proto  = (const float*)d_in[4];
    float* out  = (float*)d_out;
    float* ws_f = (float*)d_ws;

    float*  logits  = ws_f;
    float*  e_arr   = ws_f + NROWS;
    int*    b_arr   = (int*)(ws_f + 2 * NROWS);
    float2* ste     = (float2*)(ws_f + 3 * NROWS);
    int*    offsets = (int*)(ws_f + 5 * NROWS);
    int*    cursor  = offsets + KB + 1;
    float*  S       = (float*)(cursor + KB);
    float*  acc     = S + KB;
    int*    done    = (int*)(acc + 2);

    k_logits<<<NROWS / 4, 256, 0, stream>>>(feats, proto, times,
                                            logits, e_arr, b_arr, acc, done);
    k_scan<<<1, 1024, 0, stream>>>(b_arr, e_arr, offsets, cursor, S);
    k_scatter<<<NROWS / 256, 256, 0, stream>>>(times, e_arr, b_arr, cursor, ste);
    k_denom_loss<<<NROWS / 256, 256, 0, stream>>>(times, events, w, logits,
                                                  b_arr, offsets, S, ste,
                                                  acc, done, out);
}

// Round 4
// 92.634 us; speedup vs baseline: 1.1678x; 1.1678x over previous
//
#include <hip/hip_runtime.h>
#include <math.h>

#define NROWS 16384
#define KB 1024   // time buckets; floor(t*KB) monotone in t =>
                  // bucket(j) > bucket(i) => t_j > t_i exactly.

__device__ __forceinline__ float wave_reduce_sum(float v) {
    #pragma unroll
    for (int m = 32; m >= 1; m >>= 1) v += __shfl_xor(v, m, 64);
    return v;
}

__device__ __forceinline__ int bucket_of(float t) {
    int b = (int)(t * (float)KB);          // t in [0,1)
    return min(max(b, 0), KB - 1);
}

// Node 0: zero hist/esum/acc/done (ws is poisoned 0xAA each iteration).
__global__ __launch_bounds__(1024) void k_init(
    int* __restrict__ hist, float* __restrict__ esum,
    float* __restrict__ acc, int* __restrict__ done)
{
    int t = threadIdx.x;
    hist[t] = 0;
    esum[t] = 0.0f;
    if (t < 2) acc[t] = 0.0f;
    if (t == 2) *done = 0;
}

// Node 1: wave-per-row logits+exp+bucket; histogram via grid-parallel
// global atomics (2048 distinct addresses, L2-resident).
__global__ __launch_bounds__(256) void k_logits(
    const float* __restrict__ feats, const float* __restrict__ proto,
    const float* __restrict__ times,
    float* __restrict__ logits, float* __restrict__ e_arr,
    int* __restrict__ b_arr, int* __restrict__ hist, float* __restrict__ esum)
{
    int wave = threadIdx.x >> 6, lane = threadIdx.x & 63;
    int row = blockIdx.x * 4 + wave;
    float2 f = ((const float2*)feats)[row * 64 + lane];
    float2 p = ((const float2*)proto)[lane];
    float d  = f.x * p.x + f.y * p.y;
    float n2 = f.x * f.x + f.y * f.y;
    float p2 = p.x * p.x + p.y * p.y;
    d  = wave_reduce_sum(d);
    n2 = wave_reduce_sum(n2);
    p2 = wave_reduce_sum(p2);
    if (lane == 0) {
        float invpn = 1.0f / fmaxf(sqrtf(p2), 1e-12f);
        float invfn = 1.0f / fmaxf(sqrtf(n2), 1e-12f);
        float logit = (d * invpn * invfn) / 0.07f;
        float e     = expf(logit);
        int   b     = bucket_of(times[row]);
        logits[row] = logit;
        e_arr[row]  = e;
        b_arr[row]  = b;
        atomicAdd(&hist[b], 1);
        atomicAdd(&esum[b], e);
    }
}

// Node 2: single block, scan ONLY the 1024 bucket entries:
// exclusive offsets/cursor + strict-suffix e-sums S[b].
__global__ __launch_bounds__(1024) void k_scan(
    const int* __restrict__ hist, const float* __restrict__ esum,
    int* __restrict__ offsets, int* __restrict__ cursor, float* __restrict__ S)
{
    __shared__ int   wbh[16];
    __shared__ float wbe[16];
    __shared__ float tot_sh;
    int t = threadIdx.x;
    int   h = hist[t];
    float e = esum[t];
    int   hi = h;
    float ei = e;
    int lane = t & 63, wid = t >> 6;
    #pragma unroll
    for (int d = 1; d < 64; d <<= 1) {
        int   hu = __shfl_up(hi, d, 64);
        float eu = __shfl_up(ei, d, 64);
        if (lane >= d) { hi += hu; ei += eu; }
    }
    if (lane == 63) { wbh[wid] = hi; wbe[wid] = ei; }
    __syncthreads();
    if (t == 0) {
        int hb = 0; float eb = 0.0f;
        #pragma unroll
        for (int k = 0; k < 16; ++k) {
            int hn = wbh[k]; float en = wbe[k];
            wbh[k] = hb; wbe[k] = eb;
            hb += hn; eb += en;
        }
        tot_sh = eb;
    }
    __syncthreads();
    hi += wbh[wid];            // inclusive prefix
    ei += wbe[wid];
    offsets[t] = hi - h;       // exclusive
    cursor[t]  = hi - h;
    S[t] = tot_sh - ei;        // strict suffix sum of e over higher buckets
    if (t == KB - 1) offsets[KB] = hi;
}

// Node 3: scatter rows into bucket-sorted CSR as (t, e) pairs.
__global__ __launch_bounds__(256) void k_scatter(
    const float* __restrict__ times, const float* __restrict__ e_arr,
    const int* __restrict__ b_arr, int* __restrict__ cursor,
    float2* __restrict__ ste)
{
    int r = blockIdx.x * 256 + threadIdx.x;
    int b = b_arr[r];
    int pos = atomicAdd(&cursor[b], 1);
    ste[pos] = make_float2(times[r], e_arr[r]);
}

// Node 4: denom = strict-suffix + exact own-bucket compare; loss reduce; final.
__global__ __launch_bounds__(256) void k_denom_loss(
    const float* __restrict__ times, const int* __restrict__ events,
    const float* __restrict__ w, const float* __restrict__ logits,
    const int* __restrict__ b_arr, const int* __restrict__ offsets,
    const float* __restrict__ S, const float2* __restrict__ ste,
    float* __restrict__ acc, int* __restrict__ done, float* __restrict__ out)
{
    int i = blockIdx.x * 256 + threadIdx.x;
    float ti = times[i];
    int b = b_arr[i];
    float denom = S[b];
    int p1 = offsets[b + 1];
    for (int p = offsets[b]; p < p1; ++p) {
        float2 v = ste[p];
        denom += (v.x >= ti) ? v.y : 0.0f;
    }
    float ev = (float)events[i];
    float wv = ev * w[i];
    float loss = -(logits[i] - logf(denom + 1e-8f)) * wv;
    loss = wave_reduce_sum(loss);
    wv   = wave_reduce_sum(wv);
    __shared__ float s1[4], s2[4];
    int wave = threadIdx.x >> 6, lane = threadIdx.x & 63;
    if (lane == 0) { s1[wave] = loss; s2[wave] = wv; }
    __syncthreads();
    if (threadIdx.x == 0) {
        atomicAdd(&acc[0], s1[0] + s1[1] + s1[2] + s1[3]);
        atomicAdd(&acc[1], s2[0] + s2[1] + s2[2] + s2[3]);
        __threadfence();
        int ticket = atomicAdd(done, 1);
        if (ticket == (int)gridDim.x - 1) {
            __threadfence();
            float L = atomicAdd(&acc[0], 0.0f);
            float W = atomicAdd(&acc[1], 0.0f);
            out[0] = L / (W + 1e-8f);
        }
    }
}

extern "C" void kernel_launch(void* const* d_in, const int* in_sizes, int n_in,
                              void* d_out, int out_size, void* d_ws, size_t ws_size,
                              hipStream_t stream) {
    const float* feats  = (const float*)d_in[0];
    const float* times  = (const float*)d_in[1];
    const int*   events = (const int*)d_in[2];
    const float* w      = (const float*)d_in[3];
    const float* proto  = (const float*)d_in[4];
    float* out  = (float*)d_out;
    float* ws_f = (float*)d_ws;

    float*  logits  = ws_f;                       // N
    float*  e_arr   = ws_f + NROWS;               // N
    int*    b_arr   = (int*)(ws_f + 2 * NROWS);   // N
    float2* ste     = (float2*)(ws_f + 3 * NROWS);// 2N floats
    int*    hist    = (int*)(ws_f + 5 * NROWS);   // KB
    int*    offsets = hist + KB;                  // KB+1
    int*    cursor  = offsets + KB + 1;           // KB
    float*  esum    = (float*)(cursor + KB);      // KB
    float*  S       = esum + KB;                  // KB
    float*  acc     = S + KB;                     // 2
    int*    done    = (int*)(acc + 2);            // 1

    k_init<<<1, 1024, 0, stream>>>(hist, esum, acc, done);
    k_logits<<<NROWS / 4, 256, 0, stream>>>(feats, proto, times,
                                            logits, e_arr, b_arr, hist, esum);
    k_scan<<<1, 1024, 0, stream>>>(hist, esum, offsets, cursor, S);
    k_scatter<<<NROWS / 256, 256, 0, stream>>>(times, e_arr, b_arr, cursor, ste);
    k_denom_loss<<<NROWS / 256, 256, 0, stream>>>(times, events, w, logits,
                                                  b_arr, offsets, S, ste,
                                                  acc, done, out);
}